// Round 2
// baseline (596.700 us; speedup 1.0000x reference)
//
#include <hip/hip_runtime.h>
#include <cmath>

// B=2, S=2048, DIM=1024, NH=16, HD=64, BLK=32, WIN=512.  M = B*S = 4096.
// Structure exploited:
//  - sel branch output == win branch output (sel projections dead)
//  - window attn: rows i<1536 fully masked -> uniform mean of v_win[1536:]
//  - comp attn: rows i<1984 fully masked -> uniform mean of 64 compressed v rows
// Precision plan: GEMMs in bf16 MFMA (fp32 accumulate), everything else fp32.

#define QS 3072   // QKV buffer row stride (3 projections * 1024)

typedef unsigned short ushort_t;
typedef __attribute__((ext_vector_type(4))) float f32x4;
typedef __attribute__((ext_vector_type(8))) short s8b;       // 8 bf16 = 4 VGPR
typedef __attribute__((ext_vector_type(8))) unsigned short u16x8;

__device__ __forceinline__ unsigned short f2bf(float f) {
    unsigned u = __float_as_uint(f);
    u += 0x7FFF + ((u >> 16) & 1);   // round-to-nearest-even
    return (unsigned short)(u >> 16);
}

__device__ __forceinline__ void gload16(const void* g, void* l) {
    __builtin_amdgcn_global_load_lds(
        (const __attribute__((address_space(1))) unsigned int*)g,
        (__attribute__((address_space(3))) unsigned int*)l, 16, 0, 0);
}

// ---------------------------------------------------------------------------
// fp32 -> bf16 convert (8 elements / thread)
// ---------------------------------------------------------------------------
__global__ __launch_bounds__(256) void cvt_bf16(const float* __restrict__ in,
                                                ushort_t* __restrict__ outp) {
    int id = blockIdx.x * 256 + threadIdx.x;
    const float4* xp = (const float4*)in;
    float4 a = xp[id * 2], b = xp[id * 2 + 1];
    u16x8 o;
    o[0] = f2bf(a.x); o[1] = f2bf(a.y); o[2] = f2bf(a.z); o[3] = f2bf(a.w);
    o[4] = f2bf(b.x); o[5] = f2bf(b.y); o[6] = f2bf(b.z); o[7] = f2bf(b.w);
    *(u16x8*)&outp[id * 8] = o;
}

// ---------------------------------------------------------------------------
// Weight convert + transpose: WT[wi][n][k] = bf16(w_wi[k][n]).  32x32 tiles.
// ---------------------------------------------------------------------------
struct WPtrs { const float* p[7]; };

__global__ __launch_bounds__(256) void wt_cvt(WPtrs wp, ushort_t* __restrict__ WT) {
    __shared__ float T[32][33];
    const int wi = blockIdx.z;
    const float* w = wp.p[wi];
    const int k0 = blockIdx.y * 32, n0 = blockIdx.x * 32;
    const int t = threadIdx.x;
    const int row = t >> 3, c4 = t & 7;
    float4 v = *(const float4*)&w[(size_t)(k0 + row) * 1024 + n0 + c4 * 4];
    T[row][c4 * 4 + 0] = v.x; T[row][c4 * 4 + 1] = v.y;
    T[row][c4 * 4 + 2] = v.z; T[row][c4 * 4 + 3] = v.w;
    __syncthreads();
    ushort4 o;
    o.x = f2bf(T[c4 * 4 + 0][row]);
    o.y = f2bf(T[c4 * 4 + 1][row]);
    o.z = f2bf(T[c4 * 4 + 2][row]);
    o.w = f2bf(T[c4 * 4 + 3][row]);
    *(ushort4*)&WT[((size_t)wi << 20) + (size_t)(n0 + row) * 1024 + k0 + c4 * 4] = o;
}

// ---------------------------------------------------------------------------
// bf16 MFMA GEMM (m97 structure): C[4096 x N] = A[4096x1024] @ W, W given as
// W^T bf16 tiles of [n][k].  WT may hold several 1024x1024 weights back to
// back; block n0 selects weight (n0>>10).  128x128 tile, BK=32, 256 thr.
// ---------------------------------------------------------------------------
__global__ __launch_bounds__(256) void gemm_mfma(const ushort_t* __restrict__ A,
                                                 const ushort_t* __restrict__ WT,
                                                 float* __restrict__ C, int ldc) {
    __shared__ ushort_t Al[128 * 32];   // [row][k] 64B rows
    __shared__ ushort_t Bl[128 * 32];   // [n][k]
    const int tid = threadIdx.x;
    const int wave = tid >> 6, lane = tid & 63;
    const int m0 = blockIdx.y * 128;
    const int n0 = blockIdx.x * 128;
    const ushort_t* B = WT + ((size_t)(n0 >> 10) << 20) + (size_t)(n0 & 1023) * 1024;
    const int wr = wave >> 1, wc = wave & 1;   // 2x2 waves of 64x64
    f32x4 acc[4][4];
#pragma unroll
    for (int i = 0; i < 4; ++i)
#pragma unroll
        for (int j = 0; j < 4; ++j) acc[i][j] = (f32x4)0.f;

    for (int k0 = 0; k0 < 1024; k0 += 32) {
#pragma unroll
        for (int it = 0; it < 2; ++it) {
            const int chunk = it * 256 + wave * 64 + lane;
            const int row = chunk >> 2, slot = chunk & 3;
            gload16(A + (size_t)(m0 + row) * 1024 + k0 + slot * 8,
                    (char*)Al + (size_t)(it * 256 + wave * 64) * 16);
            gload16(B + (size_t)row * 1024 + k0 + slot * 8,
                    (char*)Bl + (size_t)(it * 256 + wave * 64) * 16);
        }
        __syncthreads();   // compiler drains vmcnt here
        s8b af[4], bf[4];
        const int lr = lane & 15, lk = (lane >> 4) * 8;
#pragma unroll
        for (int f = 0; f < 4; ++f) {
            af[f] = *(const s8b*)&Al[(wr * 64 + f * 16 + lr) * 32 + lk];
            bf[f] = *(const s8b*)&Bl[(wc * 64 + f * 16 + lr) * 32 + lk];
        }
#pragma unroll
        for (int mi = 0; mi < 4; ++mi)
#pragma unroll
            for (int ni = 0; ni < 4; ++ni)
                acc[mi][ni] = __builtin_amdgcn_mfma_f32_16x16x32_bf16(
                    af[mi], bf[ni], acc[mi][ni], 0, 0, 0);
        __syncthreads();
    }
    const int lr = lane & 15, lq = lane >> 4;
#pragma unroll
    for (int mi = 0; mi < 4; ++mi)
#pragma unroll
        for (int ni = 0; ni < 4; ++ni) {
            const int cm = m0 + wr * 64 + mi * 16 + lq * 4;
            const int cn = n0 + wc * 64 + ni * 16 + lr;
#pragma unroll
            for (int r = 0; r < 4; ++r)
                C[(size_t)(cm + r) * ldc + cn] = acc[mi][ni][r];
        }
}

// ---------------------------------------------------------------------------
// RoPE in-place on q (offset 0) and k (offset 1024) inside QKV (stride QS).
// ---------------------------------------------------------------------------
__global__ __launch_bounds__(256) void rope2(float* __restrict__ qkv,
                                             const float* __restrict__ cosb,
                                             const float* __restrict__ sinb) {
    unsigned id = blockIdx.x * 256 + threadIdx.x;   // < 2,097,152
    int d = id & 31, h = (id >> 5) & 15, m = (int)(id >> 9);
    int s = m & 2047;
    float* T = qkv + (blockIdx.y ? 1024 : 0);
    float c = cosb[s * 32 + d], sn = sinb[s * 32 + d];
    size_t base = (size_t)m * QS + h * 64 + d;
    float t1 = T[base], t2 = T[base + 32];
    T[base] = t1 * c - t2 * sn;
    T[base + 32] = t2 * c + t1 * sn;
}

// ---------------------------------------------------------------------------
// Gates: softmax(x @ w_gate); g1 = g0+g2 (win+sel), g2 = g1 (comp).
// ---------------------------------------------------------------------------
__global__ __launch_bounds__(256) void gates_k(const float* __restrict__ x,
                                               const float* __restrict__ wg,
                                               float* __restrict__ g1,
                                               float* __restrict__ g2) {
    int lane = threadIdx.x & 63;
    int m = blockIdx.x * 4 + (threadIdx.x >> 6);
    float s0 = 0.f, s1 = 0.f, s2 = 0.f;
#pragma unroll
    for (int it = 0; it < 16; ++it) {
        int d = it * 64 + lane;
        float xv = x[(size_t)m * 1024 + d];
        s0 += xv * wg[d * 3 + 0];
        s1 += xv * wg[d * 3 + 1];
        s2 += xv * wg[d * 3 + 2];
    }
    for (int off = 32; off > 0; off >>= 1) {
        s0 += __shfl_xor(s0, off);
        s1 += __shfl_xor(s1, off);
        s2 += __shfl_xor(s2, off);
    }
    if (lane == 0) {
        float mx = fmaxf(s0, fmaxf(s1, s2));
        float e0 = __expf(s0 - mx), e1 = __expf(s1 - mx), e2 = __expf(s2 - mx);
        float inv = 1.f / (e0 + e1 + e2);
        g1[m] = (e0 + e2) * inv;
        g2[m] = e1 * inv;
    }
}

// mean of v_win over last 512 positions per (b,h)
__global__ void vmean_win_k(const float* __restrict__ v, float* __restrict__ vmean) {
    int bh = blockIdx.x;
    int b = bh >> 4, h = bh & 15;
    int d = threadIdx.x;
    float a = 0.f;
#pragma unroll 8
    for (int p = 0; p < 512; ++p)
        a += v[(size_t)(b * 2048 + 1536 + p) * QS + h * 64 + d];
    vmean[bh * 64 + d] = a * (1.f / 512.f);
}

// rows i < 1536 : FIN = g1 * vmean
__global__ void win_const_k(const float* __restrict__ vmean,
                            const float* __restrict__ g1,
                            float* __restrict__ fin) {
    size_t id = (size_t)blockIdx.x * 256 + threadIdx.x;   // < 2*1536*1024
    int col = id & 1023;
    int row = (int)(id >> 10);        // b*1536 + i
    int b = row >= 1536;
    int i = row - b * 1536;
    int h = col >> 6, d = col & 63;
    fin[((size_t)(b * 2048 + i) << 10) + col] =
        g1[b * 2048 + i] * vmean[((b << 4) + h) * 64 + d];
}

// ---------------------------------------------------------------------------
// Window attention rows 1536..2047.  8 lanes per query row; 64 rows / block.
// grid (chunk=8, bh=32), 512 threads.  FIN = g1 * out_win.
// ---------------------------------------------------------------------------
__global__ __launch_bounds__(512) void win_attn(const float* __restrict__ qkv,
                                                const float* __restrict__ g1,
                                                float* __restrict__ fin) {
    __shared__ float Ks[64][72];
    __shared__ float Vs[64][72];
    const int chunk = blockIdx.x;      // 0..7
    const int bh = blockIdx.y;         // 0..31
    const int b = bh >> 4, h = bh & 15;
    const int tid = threadIdx.x;
    const int r = tid >> 3, p = tid & 7;
    const int i = 1536 + chunk * 64 + r;
    const float* qrow = qkv + (size_t)(b * 2048 + i) * QS + h * 64 + p * 8;
    float qreg[8];
    *(float4*)&qreg[0] = *(const float4*)qrow;
    *(float4*)&qreg[4] = *(const float4*)(qrow + 4);
    float accv[8] = {0.f, 0.f, 0.f, 0.f, 0.f, 0.f, 0.f, 0.f};
    float mrun = -1e30f, lrun = 0.f;
    const float* kg = qkv + 1024;
    const float* vg = qkv + 2048;
    for (int jt = 0; jt <= chunk; ++jt) {
        __syncthreads();
        {
            const size_t grow = (size_t)(b * 2048 + 1536 + jt * 64 + r) * QS + h * 64 + p * 8;
            *(float4*)&Ks[r][p * 8]     = *(const float4*)(kg + grow);
            *(float4*)&Ks[r][p * 8 + 4] = *(const float4*)(kg + grow + 4);
            *(float4*)&Vs[r][p * 8]     = *(const float4*)(vg + grow);
            *(float4*)&Vs[r][p * 8 + 4] = *(const float4*)(vg + grow + 4);
        }
        __syncthreads();
        const int jmax = (jt < chunk) ? 64 : (r + 1);
        for (int j = 0; j < jmax; ++j) {
            float4 k0v = *(const float4*)&Ks[j][p * 8];
            float4 k1v = *(const float4*)&Ks[j][p * 8 + 4];
            float s = qreg[0] * k0v.x + qreg[1] * k0v.y + qreg[2] * k0v.z + qreg[3] * k0v.w
                    + qreg[4] * k1v.x + qreg[5] * k1v.y + qreg[6] * k1v.z + qreg[7] * k1v.w;
            s += __shfl_xor(s, 1);
            s += __shfl_xor(s, 2);
            s += __shfl_xor(s, 4);
            s *= 0.125f;
            float mn = fmaxf(mrun, s);
            float sc = __expf(mrun - mn);
            float pe = __expf(s - mn);
            lrun = lrun * sc + pe;
            float4 v0 = *(const float4*)&Vs[j][p * 8];
            float4 v1 = *(const float4*)&Vs[j][p * 8 + 4];
            accv[0] = accv[0] * sc + pe * v0.x; accv[1] = accv[1] * sc + pe * v0.y;
            accv[2] = accv[2] * sc + pe * v0.z; accv[3] = accv[3] * sc + pe * v0.w;
            accv[4] = accv[4] * sc + pe * v1.x; accv[5] = accv[5] * sc + pe * v1.y;
            accv[6] = accv[6] * sc + pe * v1.z; accv[7] = accv[7] * sc + pe * v1.w;
            mrun = mn;
        }
    }
    float g = g1[b * 2048 + i] / lrun;
    float4 o0, o1;
    o0.x = accv[0] * g; o0.y = accv[1] * g; o0.z = accv[2] * g; o0.w = accv[3] * g;
    o1.x = accv[4] * g; o1.y = accv[5] * g; o1.z = accv[6] * g; o1.w = accv[7] * g;
    float* frow = fin + (size_t)(b * 2048 + i) * 1024 + h * 64 + p * 8;
    *(float4*)frow = o0;
    *(float4*)(frow + 4) = o1;
}

// ---------------------------------------------------------------------------
// Compressed k/v (fp32): kc[bh,jb,:] = sum_{p,d} k[jb*32+p, d] * w[p*64+d][:]
// ---------------------------------------------------------------------------
__global__ __launch_bounds__(64) void comp_mlp(const float* __restrict__ k,
                                               const float* __restrict__ v,
                                               const float* __restrict__ w,
                                               float* __restrict__ kc,
                                               float* __restrict__ vc) {
    int blk = blockIdx.x;
    int jb = blk & 63;
    int bh = blk >> 6;
    int b = bh >> 4, h = bh & 15;
    int dout = threadIdx.x;
    float ak = 0.f, av = 0.f;
    for (int p = 0; p < 32; ++p) {
        const float* krow = &k[(size_t)(b * 2048 + jb * 32 + p) * QS + h * 64];
        const float* vrow = &v[(size_t)(b * 2048 + jb * 32 + p) * QS + h * 64];
#pragma unroll 8
        for (int d = 0; d < 64; ++d) {
            float wv = w[(size_t)(p * 64 + d) * 64 + dout];
            ak += krow[d] * wv;
            av += vrow[d] * wv;
        }
    }
    kc[(size_t)blk * 64 + dout] = ak;
    vc[(size_t)blk * 64 + dout] = av;
}

__global__ void mean_vc_k(const float* __restrict__ vc, float* __restrict__ mvc) {
    int bh = blockIdx.x;
    int d = threadIdx.x;
    float a = 0.f;
#pragma unroll 8
    for (int jb = 0; jb < 64; ++jb) a += vc[((size_t)bh * 64 + jb) * 64 + d];
    mvc[bh * 64 + d] = a * (1.f / 64.f);
}

// rows i < 1984 : FIN += g2 * mean_vc
__global__ void comp_const_k(const float* __restrict__ mvc,
                             const float* __restrict__ g2,
                             float* __restrict__ fin) {
    size_t id = (size_t)blockIdx.x * 256 + threadIdx.x;   // < 2*1984*1024
    int col = id & 1023;
    int row = (int)(id >> 10);
    int b = row >= 1984;
    int i = row - b * 1984;
    int h = col >> 6, d = col & 63;
    fin[((size_t)(b * 2048 + i) << 10) + col] +=
        g2[b * 2048 + i] * mvc[((b << 4) + h) * 64 + d];
}

// rows 1984..2047 per batch: row 1984+t attends compressed blocks 0..t
__global__ __launch_bounds__(64) void comp_attn(const float* __restrict__ q,
                                                const float* __restrict__ kc,
                                                const float* __restrict__ vc,
                                                const float* __restrict__ g2,
                                                float* __restrict__ fin) {
    __shared__ float Ks[64][64];
    __shared__ float Vs[64][64];
    int bh = blockIdx.x;
    int b = bh >> 4, h = bh & 15;
    int t = threadIdx.x;
    for (int j = 0; j < 64; ++j) {
        Ks[j][t] = kc[((size_t)bh * 64 + j) * 64 + t];
        Vs[j][t] = vc[((size_t)bh * 64 + j) * 64 + t];
    }
    __syncthreads();
    int i = 1984 + t;
    const float* qrow = &q[(size_t)(b * 2048 + i) * QS + h * 64];
    float qreg[64];
#pragma unroll
    for (int d4 = 0; d4 < 16; ++d4) {
        float4 tt = *reinterpret_cast<const float4*>(&qrow[d4 * 4]);
        qreg[d4 * 4 + 0] = tt.x; qreg[d4 * 4 + 1] = tt.y;
        qreg[d4 * 4 + 2] = tt.z; qreg[d4 * 4 + 3] = tt.w;
    }
    float accv[64];
#pragma unroll
    for (int d = 0; d < 64; ++d) accv[d] = 0.f;
    float mrun = -1e30f, lrun = 0.f;
    for (int j = 0; j <= t; ++j) {
        float s0 = 0.f, s1 = 0.f, s2 = 0.f, s3 = 0.f;
#pragma unroll
        for (int d4 = 0; d4 < 16; ++d4) {
            float4 kv = *reinterpret_cast<const float4*>(&Ks[j][d4 * 4]);
            s0 += qreg[d4 * 4 + 0] * kv.x;
            s1 += qreg[d4 * 4 + 1] * kv.y;
            s2 += qreg[d4 * 4 + 2] * kv.z;
            s3 += qreg[d4 * 4 + 3] * kv.w;
        }
        float s = ((s0 + s1) + (s2 + s3)) * 0.125f;
        float mn = fmaxf(mrun, s);
        float sc = __expf(mrun - mn);
        float pe = __expf(s - mn);
        lrun = lrun * sc + pe;
#pragma unroll
        for (int d4 = 0; d4 < 16; ++d4) {
            float4 vv = *reinterpret_cast<const float4*>(&Vs[j][d4 * 4]);
            accv[d4 * 4 + 0] = accv[d4 * 4 + 0] * sc + pe * vv.x;
            accv[d4 * 4 + 1] = accv[d4 * 4 + 1] * sc + pe * vv.y;
            accv[d4 * 4 + 2] = accv[d4 * 4 + 2] * sc + pe * vv.z;
            accv[d4 * 4 + 3] = accv[d4 * 4 + 3] * sc + pe * vv.w;
        }
        mrun = mn;
    }
    float g = g2[b * 2048 + i] / lrun;
    float* frow = &fin[((size_t)(b * 2048 + i)) * 1024 + h * 64];
#pragma unroll
    for (int d = 0; d < 64; ++d) frow[d] += g * accv[d];
}

// ---------------------------------------------------------------------------
extern "C" void kernel_launch(void* const* d_in, const int* in_sizes, int n_in,
                              void* d_out, int out_size, void* d_ws, size_t ws_size,
                              hipStream_t stream) {
    const float* x       = (const float*)d_in[0];
    const float* wq_win  = (const float*)d_in[1];
    const float* wk_win  = (const float*)d_in[2];
    const float* wv_win  = (const float*)d_in[3];
    // d_in[4..6] sel weights unused (out_sel == out_win)
    const float* wq_comp = (const float*)d_in[7];
    const float* wk_comp = (const float*)d_in[8];
    const float* wv_comp = (const float*)d_in[9];
    const float* w_mlp   = (const float*)d_in[10];
    const float* w_gate  = (const float*)d_in[11];
    const float* wo      = (const float*)d_in[12];
    const float* cosb    = (const float*)d_in[13];
    const float* sinb    = (const float*)d_in[14];
    float* out = (float*)d_out;

    char* wsb = (char*)d_ws;
    ushort_t* XB = (ushort_t*)wsb;                        // 8 MB  bf16 x
    ushort_t* WT = (ushort_t*)(wsb + (8u << 20));         // 14 MB 7 transposed bf16 weights
    float* QKV   = (float*)(wsb + (22u << 20));           // 48 MB [4096][3072]
    float* FIN   = (float*)(wsb + (70u << 20));           // 16 MB [4096][1024]
    ushort_t* FB = (ushort_t*)(wsb + (86u << 20));        // 8 MB  bf16 FIN
    float* KC    = (float*)(wsb + (94u << 20));           // 512 KB
    float* VC    = KC + 131072;                           // 512 KB
    float* VMW   = VC + 131072;
    float* MVC   = VMW + 2048;
    float* G1    = MVC + 2048;
    float* G2    = G1 + 4096;

    WPtrs wp;
    wp.p[0] = wq_win;  wp.p[1] = wk_win;  wp.p[2] = wv_win;
    wp.p[3] = wq_comp; wp.p[4] = wk_comp; wp.p[5] = wv_comp;
    wp.p[6] = wo;

    cvt_bf16<<<2048, 256, 0, stream>>>(x, XB);
    wt_cvt<<<dim3(32, 32, 7), 256, 0, stream>>>(wp, WT);
    gates_k<<<1024, 256, 0, stream>>>(x, w_gate, G1, G2);

    // ---- window branch ----
    gemm_mfma<<<dim3(24, 32), 256, 0, stream>>>(XB, WT, QKV, QS);
    rope2<<<dim3(8192, 2), 256, 0, stream>>>(QKV, cosb, sinb);
    vmean_win_k<<<32, 64, 0, stream>>>(QKV + 2048, VMW);
    win_const_k<<<12288, 256, 0, stream>>>(VMW, G1, FIN);
    win_attn<<<dim3(8, 32), 512, 0, stream>>>(QKV, G1, FIN);

    // ---- comp branch (reuses QKV) ----
    gemm_mfma<<<dim3(24, 32), 256, 0, stream>>>(XB, WT + 3 * 1048576, QKV, QS);
    rope2<<<dim3(8192, 2), 256, 0, stream>>>(QKV, cosb, sinb);
    comp_mlp<<<2048, 64, 0, stream>>>(QKV + 1024, QKV + 2048, w_mlp, KC, VC);
    mean_vc_k<<<32, 64, 0, stream>>>(VC, MVC);
    comp_const_k<<<15872, 256, 0, stream>>>(MVC, G2, FIN);
    comp_attn<<<32, 64, 0, stream>>>(QKV, KC, VC, G2, FIN);

    // ---- output projection ----
    cvt_bf16<<<2048, 256, 0, stream>>>(FIN, FB);
    gemm_mfma<<<dim3(8, 32), 256, 0, stream>>>(FB, WT + 6 * 1048576, out, 1024);
}

// Round 5
// 479.779 us; speedup vs baseline: 1.2437x; 1.2437x over previous
//
#include <hip/hip_runtime.h>
#include <cmath>

// B=2, S=2048, DIM=1024, NH=16, HD=64, BLK=32, WIN=512.  M = B*S = 4096.
// Structure exploited:
//  - sel branch output == win branch output (sel projections dead)
//  - window attn: rows i<1536 fully masked -> uniform mean of v_win[1536:]
//  - comp attn: rows i<1984 fully masked -> uniform mean of 64 compressed v rows
// Precision: GEMMs bf16 MFMA (fp32 accum), attention/softmax fp32.
// RoPE fused into GEMM epilogue; final mix assembled directly to bf16.

#define QS 3072   // QKV row stride (q|k|v)

typedef unsigned short ushort_t;
typedef __attribute__((ext_vector_type(4))) float f32x4;
typedef __attribute__((ext_vector_type(8))) short s8b;
typedef __attribute__((ext_vector_type(8))) unsigned short u16x8;

__device__ __forceinline__ unsigned short f2bf(float f) {
    unsigned u = __float_as_uint(f);
    u += 0x7FFF + ((u >> 16) & 1);
    return (unsigned short)(u >> 16);
}

__device__ __forceinline__ void gload16(const void* g, void* l) {
    __builtin_amdgcn_global_load_lds(
        (const __attribute__((address_space(1))) unsigned int*)g,
        (__attribute__((address_space(3))) unsigned int*)l, 16, 0, 0);
}

// ---------------------------------------------------------------------------
// fp32 -> bf16 (8 elem / thread)
// ---------------------------------------------------------------------------
__global__ __launch_bounds__(256) void cvt_bf16(const float* __restrict__ in,
                                                ushort_t* __restrict__ outp) {
    int id = blockIdx.x * 256 + threadIdx.x;
    const float4* xp = (const float4*)in;
    float4 a = xp[id * 2], b = xp[id * 2 + 1];
    u16x8 o;
    o[0] = f2bf(a.x); o[1] = f2bf(a.y); o[2] = f2bf(a.z); o[3] = f2bf(a.w);
    o[4] = f2bf(b.x); o[5] = f2bf(b.y); o[6] = f2bf(b.z); o[7] = f2bf(b.w);
    *(u16x8*)&outp[id * 8] = o;
}

// ---------------------------------------------------------------------------
// Weight convert + transpose: WT[wi][n][k] = bf16(w_wi[k][n])
// ---------------------------------------------------------------------------
struct WPtrs { const float* p[7]; };

__global__ __launch_bounds__(256) void wt_cvt(WPtrs wp, ushort_t* __restrict__ WT) {
    __shared__ float T[32][33];
    const int wi = blockIdx.z;
    const float* w = wp.p[wi];
    const int k0 = blockIdx.y * 32, n0 = blockIdx.x * 32;
    const int t = threadIdx.x;
    const int row = t >> 3, c4 = t & 7;
    float4 v = *(const float4*)&w[(size_t)(k0 + row) * 1024 + n0 + c4 * 4];
    T[row][c4 * 4 + 0] = v.x; T[row][c4 * 4 + 1] = v.y;
    T[row][c4 * 4 + 2] = v.z; T[row][c4 * 4 + 3] = v.w;
    __syncthreads();
    ushort4 o;
    o.x = f2bf(T[c4 * 4 + 0][row]);
    o.y = f2bf(T[c4 * 4 + 1][row]);
    o.z = f2bf(T[c4 * 4 + 2][row]);
    o.w = f2bf(T[c4 * 4 + 3][row]);
    *(ushort4*)&WT[((size_t)wi << 20) + (size_t)(n0 + row) * 1024 + k0 + c4 * 4] = o;
}

// ---------------------------------------------------------------------------
// bf16 MFMA GEMM, m97 structure. 128x128 tile, BK=32, 256 thr, 2x2 waves.
// MODE 1: fused RoPE on output columns < 2048 (q and k of QKV).
// ---------------------------------------------------------------------------
template <int MODE>
__global__ __launch_bounds__(256) void gemm_mfma(const ushort_t* __restrict__ A,
                                                 const ushort_t* __restrict__ WT,
                                                 float* __restrict__ C, int ldc,
                                                 const float* __restrict__ cosT,
                                                 const float* __restrict__ sinT) {
    __shared__ ushort_t Al[128 * 32];
    __shared__ ushort_t Bl[128 * 32];
    const int tid = threadIdx.x;
    const int wave = tid >> 6, lane = tid & 63;
    const int m0 = blockIdx.y * 128;
    const int n0 = blockIdx.x * 128;
    const ushort_t* B = WT + ((size_t)(n0 >> 10) << 20) + (size_t)(n0 & 1023) * 1024;
    const int wr = wave >> 1, wc = wave & 1;
    f32x4 acc[4][4];
#pragma unroll
    for (int i = 0; i < 4; ++i)
#pragma unroll
        for (int j = 0; j < 4; ++j) acc[i][j] = (f32x4)0.f;

    for (int k0 = 0; k0 < 1024; k0 += 32) {
#pragma unroll
        for (int it = 0; it < 2; ++it) {
            const int chunk = it * 256 + wave * 64 + lane;
            const int row = chunk >> 2, slot = chunk & 3;
            gload16(A + (size_t)(m0 + row) * 1024 + k0 + slot * 8,
                    (char*)Al + (size_t)(it * 256 + wave * 64) * 16);
            gload16(B + (size_t)row * 1024 + k0 + slot * 8,
                    (char*)Bl + (size_t)(it * 256 + wave * 64) * 16);
        }
        __syncthreads();
        s8b af[4], bf[4];
        const int lr0 = lane & 15, lk = (lane >> 4) * 8;
#pragma unroll
        for (int f = 0; f < 4; ++f) {
            af[f] = *(const s8b*)&Al[(wr * 64 + f * 16 + lr0) * 32 + lk];
            bf[f] = *(const s8b*)&Bl[(wc * 64 + f * 16 + lr0) * 32 + lk];
        }
#pragma unroll
        for (int mi = 0; mi < 4; ++mi)
#pragma unroll
            for (int ni = 0; ni < 4; ++ni)
                acc[mi][ni] = __builtin_amdgcn_mfma_f32_16x16x32_bf16(
                    af[mi], bf[ni], acc[mi][ni], 0, 0, 0);
        __syncthreads();
    }
    const int lr = lane & 15, lq = lane >> 4;
    if (MODE == 1 && n0 < 2048) {   // fused RoPE (q,k columns)
#pragma unroll
        for (int mi = 0; mi < 4; ++mi)
#pragma unroll
            for (int r = 0; r < 4; ++r) {
                const int sp = (m0 + wr * 64 + mi * 16 + lq * 4 + r) & 2047;
#pragma unroll
                for (int ni = 0; ni < 2; ++ni) {
                    const int dd = ni * 16 + lr;
                    const float c = cosT[sp * 32 + dd];
                    const float sn = sinT[sp * 32 + dd];
                    const float a0 = acc[mi][ni][r], a2 = acc[mi][ni + 2][r];
                    acc[mi][ni][r]     = c * a0 - sn * a2;
                    acc[mi][ni + 2][r] = sn * a0 + c * a2;
                }
            }
    }
#pragma unroll
    for (int mi = 0; mi < 4; ++mi)
#pragma unroll
        for (int ni = 0; ni < 4; ++ni) {
            const int cm = m0 + wr * 64 + mi * 16 + lq * 4;
            const int cn = n0 + wc * 64 + ni * 16 + lr;
#pragma unroll
            for (int r = 0; r < 4; ++r)
                C[(size_t)(cm + r) * ldc + cn] = acc[mi][ni][r];
        }
}

// ---------------------------------------------------------------------------
// Gates: softmax(x @ w_gate); g1 = g0+g2 (win+sel), g2 = g1 (comp)
// ---------------------------------------------------------------------------
__global__ __launch_bounds__(256) void gates_k(const float* __restrict__ x,
                                               const float* __restrict__ wg,
                                               float* __restrict__ g1,
                                               float* __restrict__ g2) {
    int lane = threadIdx.x & 63;
    int m = blockIdx.x * 4 + (threadIdx.x >> 6);
    float s0 = 0.f, s1 = 0.f, s2 = 0.f;
#pragma unroll
    for (int it = 0; it < 16; ++it) {
        int d = it * 64 + lane;
        float xv = x[(size_t)m * 1024 + d];
        s0 += xv * wg[d * 3 + 0];
        s1 += xv * wg[d * 3 + 1];
        s2 += xv * wg[d * 3 + 2];
    }
    for (int off = 32; off > 0; off >>= 1) {
        s0 += __shfl_xor(s0, off);
        s1 += __shfl_xor(s1, off);
        s2 += __shfl_xor(s2, off);
    }
    if (lane == 0) {
        float mx = fmaxf(s0, fmaxf(s1, s2));
        float e0 = __expf(s0 - mx), e1 = __expf(s1 - mx), e2 = __expf(s2 - mx);
        float inv = 1.f / (e0 + e1 + e2);
        g1[m] = (e0 + e2) * inv;
        g2[m] = e1 * inv;
    }
}

// mean of v_win over last 512 positions per (b,h); 256 thr: 4 partial sums
__global__ __launch_bounds__(256) void vmean_win_k(const float* __restrict__ v,
                                                   float* __restrict__ vmean) {
    __shared__ float red[4][64];
    int bh = blockIdx.x;
    int b = bh >> 4, h = bh & 15;
    int d = threadIdx.x & 63, sub = threadIdx.x >> 6;
    float a = 0.f;
#pragma unroll 8
    for (int p = 0; p < 128; ++p)
        a += v[(size_t)(b * 2048 + 1536 + sub * 128 + p) * QS + h * 64 + d];
    red[sub][d] = a;
    __syncthreads();
    if (sub == 0)
        vmean[bh * 64 + d] = (red[0][d] + red[1][d] + red[2][d] + red[3][d]) * (1.f / 512.f);
}

// ---------------------------------------------------------------------------
// Window attention rows 1536..2047, tile-parallel.
// Block 256 thr = 64 rows x 4 subs; grid (chunk 0..7, bh 0..31).
// Writes OW = g1 * out_win  (rows 1536.., layout [2][512][1024]).
// ---------------------------------------------------------------------------
__global__ __launch_bounds__(256) void win_attn(const float* __restrict__ qkv,
                                                const float* __restrict__ g1,
                                                float* __restrict__ OW) {
    __shared__ float Ks[64][68];
    __shared__ float Vs[64][68];
    __shared__ float Ps[64][68];
    const int chunk = blockIdx.x, bh = blockIdx.y;
    const int b = bh >> 4, h = bh & 15;
    const int t = threadIdx.x;
    const int rq = t >> 2, sub = t & 3;
    const int i = 1536 + chunk * 64 + rq;

    const float* qrow = qkv + (size_t)(b * 2048 + i) * QS + h * 64;
    float qreg[64];
#pragma unroll
    for (int d4 = 0; d4 < 16; ++d4) {
        float4 tt = *(const float4*)&qrow[d4 * 4];
        qreg[d4 * 4 + 0] = tt.x; qreg[d4 * 4 + 1] = tt.y;
        qreg[d4 * 4 + 2] = tt.z; qreg[d4 * 4 + 3] = tt.w;
    }
    float accv[16];
#pragma unroll
    for (int dd = 0; dd < 16; ++dd) accv[dd] = 0.f;
    float mrun = -1e30f, lrun = 0.f;
    const float* kg = qkv + 1024;
    const float* vg = qkv + 2048;

    for (int jt = 0; jt <= chunk; ++jt) {
        __syncthreads();
        {
            const size_t grow = (size_t)(b * 2048 + 1536 + jt * 64 + rq) * QS + h * 64 + sub * 16;
#pragma unroll
            for (int q4 = 0; q4 < 4; ++q4) {
                *(float4*)&Ks[rq][sub * 16 + q4 * 4] = *(const float4*)(kg + grow + q4 * 4);
                *(float4*)&Vs[rq][sub * 16 + q4 * 4] = *(const float4*)(vg + grow + q4 * 4);
            }
        }
        __syncthreads();
        const bool tail = (jt == chunk);
        float s[16];
#pragma unroll
        for (int jj = 0; jj < 16; ++jj) {
            const int j = jj * 4 + sub;          // conflict-free interleave
            float s0 = 0.f, s1 = 0.f, s2 = 0.f, s3 = 0.f;
#pragma unroll
            for (int d4 = 0; d4 < 16; ++d4) {
                float4 kv = *(const float4*)&Ks[j][d4 * 4];
                s0 += qreg[d4 * 4 + 0] * kv.x;
                s1 += qreg[d4 * 4 + 1] * kv.y;
                s2 += qreg[d4 * 4 + 2] * kv.z;
                s3 += qreg[d4 * 4 + 3] * kv.w;
            }
            float sd = ((s0 + s1) + (s2 + s3)) * 0.125f;
            if (tail && j > rq) sd = -1e30f;
            s[jj] = sd;
        }
        float mx = s[0];
#pragma unroll
        for (int jj = 1; jj < 16; ++jj) mx = fmaxf(mx, s[jj]);
        mx = fmaxf(mx, __shfl_xor(mx, 1));
        mx = fmaxf(mx, __shfl_xor(mx, 2));
        const float mnew = fmaxf(mrun, mx);
        const float scl = __expf(mrun - mnew);
        float psum = 0.f;
#pragma unroll
        for (int jj = 0; jj < 16; ++jj) {
            float pe = __expf(s[jj] - mnew);
            Ps[rq][jj * 4 + sub] = pe;
            psum += pe;
        }
        psum += __shfl_xor(psum, 1);
        psum += __shfl_xor(psum, 2);
        lrun = lrun * scl + psum;
        mrun = mnew;
#pragma unroll
        for (int dd = 0; dd < 16; ++dd) accv[dd] *= scl;
        __syncthreads();
        for (int j = 0; j < 64; ++j) {
            const float pv = Ps[rq][j];
#pragma unroll
            for (int d4 = 0; d4 < 4; ++d4) {
                float4 vv = *(const float4*)&Vs[j][sub * 16 + d4 * 4];
                accv[d4 * 4 + 0] += pv * vv.x;
                accv[d4 * 4 + 1] += pv * vv.y;
                accv[d4 * 4 + 2] += pv * vv.z;
                accv[d4 * 4 + 3] += pv * vv.w;
            }
        }
    }
    const float g = g1[b * 2048 + i] / lrun;
    float* orow = OW + (size_t)(b * 512 + i - 1536) * 1024 + h * 64 + sub * 16;
#pragma unroll
    for (int d4 = 0; d4 < 4; ++d4) {
        float4 o;
        o.x = accv[d4 * 4 + 0] * g; o.y = accv[d4 * 4 + 1] * g;
        o.z = accv[d4 * 4 + 2] * g; o.w = accv[d4 * 4 + 3] * g;
        *(float4*)&orow[d4 * 4] = o;
    }
}

// ---------------------------------------------------------------------------
// Compressed k/v.  Block = (jb-group of 4, bh); 256 thr = 4 jb x 64 dout.
// K/V rows staged in LDS (coalesced); w reads amortized over 4 jb.
// kc[bh,jb,:] = sum_{p,d} k[jb*32+p, d] * w[p*64+d][:]
// ---------------------------------------------------------------------------
__global__ __launch_bounds__(256) void comp_mlp(const float* __restrict__ k,
                                                const float* __restrict__ v,
                                                const float* __restrict__ w,
                                                float* __restrict__ kc,
                                                float* __restrict__ vc) {
    __shared__ float Ks[128][64];   // 4 jb x 32 p
    __shared__ float Vs[128][64];
    const int jg = blockIdx.x;      // 0..15
    const int bh = blockIdx.y;      // 0..31
    const int b = bh >> 4, h = bh & 15;
    const int t = threadIdx.x;
    const int dout = t & 63, sub = t >> 6;   // sub: jb within group
#pragma unroll 4
    for (int rr = 0; rr < 32; ++rr) {
        const int row = sub * 32 + rr;       // 0..127
        const size_t src = (size_t)(b * 2048 + jg * 128 + row) * QS + h * 64 + dout;
        Ks[row][dout] = k[src];
        Vs[row][dout] = v[src];
    }
    __syncthreads();
    float ak = 0.f, av = 0.f;
    for (int p = 0; p < 32; ++p) {
        const float* krow = &Ks[sub * 32 + p][0];   // wave-uniform: broadcast reads
        const float* vrow = &Vs[sub * 32 + p][0];
#pragma unroll 8
        for (int d = 0; d < 64; ++d) {
            const float wv = w[(size_t)(p * 64 + d) * 64 + dout];
            ak += krow[d] * wv;
            av += vrow[d] * wv;
        }
    }
    const size_t dst = ((size_t)bh * 64 + jg * 4 + sub) * 64 + dout;
    kc[dst] = ak;
    vc[dst] = av;
}

__global__ void mean_vc_k(const float* __restrict__ vc, float* __restrict__ mvc) {
    int bh = blockIdx.x;
    int d = threadIdx.x;
    float a = 0.f;
#pragma unroll 8
    for (int jb = 0; jb < 64; ++jb) a += vc[((size_t)bh * 64 + jb) * 64 + d];
    mvc[bh * 64 + d] = a * (1.f / 64.f);
}

// ---------------------------------------------------------------------------
// Comp attention rows 1984..2047, tile-parallel (single 64-key tile).
// Block 256 thr = 64 rows x 4 subs; grid 32 (bh). OC = g2 * out_comp.
// ---------------------------------------------------------------------------
__global__ __launch_bounds__(256) void comp_attn(const float* __restrict__ qkv,
                                                 const float* __restrict__ kc,
                                                 const float* __restrict__ vc,
                                                 const float* __restrict__ g2,
                                                 float* __restrict__ OC) {
    __shared__ float Ks[64][68];
    __shared__ float Vs[64][68];
    __shared__ float Ps[64][68];
    const int bh = blockIdx.x;
    const int b = bh >> 4, h = bh & 15;
    const int t = threadIdx.x;
    const int rq = t >> 2, sub = t & 3;
    const int i = 1984 + rq;
    {
        const size_t src = ((size_t)bh * 64 + rq) * 64 + sub * 16;
#pragma unroll
        for (int q4 = 0; q4 < 4; ++q4) {
            *(float4*)&Ks[rq][sub * 16 + q4 * 4] = *(const float4*)&kc[src + q4 * 4];
            *(float4*)&Vs[rq][sub * 16 + q4 * 4] = *(const float4*)&vc[src + q4 * 4];
        }
    }
    const float* qrow = qkv + (size_t)(b * 2048 + i) * QS + h * 64;
    float qreg[64];
#pragma unroll
    for (int d4 = 0; d4 < 16; ++d4) {
        float4 tt = *(const float4*)&qrow[d4 * 4];
        qreg[d4 * 4 + 0] = tt.x; qreg[d4 * 4 + 1] = tt.y;
        qreg[d4 * 4 + 2] = tt.z; qreg[d4 * 4 + 3] = tt.w;
    }
    __syncthreads();
    float s[16];
#pragma unroll
    for (int jj = 0; jj < 16; ++jj) {
        const int j = jj * 4 + sub;
        float s0 = 0.f, s1 = 0.f, s2 = 0.f, s3 = 0.f;
#pragma unroll
        for (int d4 = 0; d4 < 16; ++d4) {
            float4 kv = *(const float4*)&Ks[j][d4 * 4];
            s0 += qreg[d4 * 4 + 0] * kv.x;
            s1 += qreg[d4 * 4 + 1] * kv.y;
            s2 += qreg[d4 * 4 + 2] * kv.z;
            s3 += qreg[d4 * 4 + 3] * kv.w;
        }
        float sd = ((s0 + s1) + (s2 + s3)) * 0.125f;
        if (j > rq) sd = -1e30f;   // causal: row 1984+rq attends blocks 0..rq
        s[jj] = sd;
    }
    float mx = s[0];
#pragma unroll
    for (int jj = 1; jj < 16; ++jj) mx = fmaxf(mx, s[jj]);
    mx = fmaxf(mx, __shfl_xor(mx, 1));
    mx = fmaxf(mx, __shfl_xor(mx, 2));
    float psum = 0.f;
#pragma unroll
    for (int jj = 0; jj < 16; ++jj) {
        float pe = __expf(s[jj] - mx);
        Ps[rq][jj * 4 + sub] = pe;
        psum += pe;
    }
    psum += __shfl_xor(psum, 1);
    psum += __shfl_xor(psum, 2);
    __syncthreads();
    float accv[16];
#pragma unroll
    for (int dd = 0; dd < 16; ++dd) accv[dd] = 0.f;
    for (int j = 0; j < 64; ++j) {
        const float pv = Ps[rq][j];
#pragma unroll
        for (int d4 = 0; d4 < 4; ++d4) {
            float4 vv = *(const float4*)&Vs[j][sub * 16 + d4 * 4];
            accv[d4 * 4 + 0] += pv * vv.x;
            accv[d4 * 4 + 1] += pv * vv.y;
            accv[d4 * 4 + 2] += pv * vv.z;
            accv[d4 * 4 + 3] += pv * vv.w;
        }
    }
    const float g = g2[b * 2048 + i] / psum;
    float* orow = OC + (size_t)(b * 64 + rq) * 1024 + h * 64 + sub * 16;
#pragma unroll
    for (int d4 = 0; d4 < 4; ++d4) {
        float4 o;
        o.x = accv[d4 * 4 + 0] * g; o.y = accv[d4 * 4 + 1] * g;
        o.z = accv[d4 * 4 + 2] * g; o.w = accv[d4 * 4 + 3] * g;
        *(float4*)&orow[d4 * 4] = o;
    }
}

// ---------------------------------------------------------------------------
// Final mix -> bf16.  8 cols / thread.
//  i<1536:        g1*vmean + g2*mvc
//  1536<=i<1984:  OW + g2*mvc        (OW pre-scaled by g1)
//  i>=1984:       OW + OC            (OC pre-scaled by g2)
// ---------------------------------------------------------------------------
__global__ __launch_bounds__(256) void assemble(const float* __restrict__ OW,
                                                const float* __restrict__ OC,
                                                const float* __restrict__ vmean,
                                                const float* __restrict__ mvc,
                                                const float* __restrict__ g1,
                                                const float* __restrict__ g2,
                                                ushort_t* __restrict__ FB) {
    int id = blockIdx.x * 256 + threadIdx.x;   // < 524288
    int m = id >> 7, cg = id & 127;
    int b = m >> 11, i = m & 2047;
    int h = cg >> 3, d0 = (cg & 7) * 8;
    int bh = b * 16 + h;
    float g1v = g1[m], g2v = g2[m];
    float vals[8];
    if (i < 1536) {
#pragma unroll
        for (int kk = 0; kk < 8; ++kk)
            vals[kk] = g1v * vmean[bh * 64 + d0 + kk] + g2v * mvc[bh * 64 + d0 + kk];
    } else if (i < 1984) {
        const float* ow = OW + (size_t)(b * 512 + i - 1536) * 1024 + cg * 8;
#pragma unroll
        for (int kk = 0; kk < 8; ++kk)
            vals[kk] = ow[kk] + g2v * mvc[bh * 64 + d0 + kk];
    } else {
        const float* ow = OW + (size_t)(b * 512 + i - 1536) * 1024 + cg * 8;
        const float* oc = OC + (size_t)(b * 64 + i - 1984) * 1024 + cg * 8;
#pragma unroll
        for (int kk = 0; kk < 8; ++kk)
            vals[kk] = ow[kk] + oc[kk];
    }
    u16x8 o;
#pragma unroll
    for (int kk = 0; kk < 8; ++kk) o[kk] = f2bf(vals[kk]);
    *(u16x8*)&FB[(size_t)m * 1024 + cg * 8] = o;
}

// ---------------------------------------------------------------------------
extern "C" void kernel_launch(void* const* d_in, const int* in_sizes, int n_in,
                              void* d_out, int out_size, void* d_ws, size_t ws_size,
                              hipStream_t stream) {
    const float* x       = (const float*)d_in[0];
    const float* wq_win  = (const float*)d_in[1];
    const float* wk_win  = (const float*)d_in[2];
    const float* wv_win  = (const float*)d_in[3];
    // d_in[4..6] sel weights unused (out_sel == out_win)
    const float* wq_comp = (const float*)d_in[7];
    const float* wk_comp = (const float*)d_in[8];
    const float* wv_comp = (const float*)d_in[9];
    const float* w_mlp   = (const float*)d_in[10];
    const float* w_gate  = (const float*)d_in[11];
    const float* wo      = (const float*)d_in[12];
    const float* cosb    = (const float*)d_in[13];
    const float* sinb    = (const float*)d_in[14];
    float* out = (float*)d_out;

    char* wsb = (char*)d_ws;
    ushort_t* XB = (ushort_t*)wsb;                      // 8 MB bf16 x
    ushort_t* WT = (ushort_t*)(wsb + (8u << 20));       // 14 MB transposed bf16 weights
    float* QKV   = (float*)(wsb + (22u << 20));         // 48 MB [4096][3072]
    ushort_t* FB = (ushort_t*)(wsb + (70u << 20));      // 8 MB bf16 mixed output
    float* OW    = (float*)(wsb + (78u << 20));         // 4 MB [2][512][1024]
    float* OC    = (float*)(wsb + (82u << 20));         // 512 KB [2][64][1024]
    float* KC    = (float*)(wsb + (83u << 20));         // 512 KB
    float* VC    = KC + 131072;                         // 512 KB
    float* VMW   = VC + 131072;
    float* MVC   = VMW + 2048;
    float* G1    = MVC + 2048;
    float* G2    = G1 + 4096;

    WPtrs wp;
    wp.p[0] = wq_win;  wp.p[1] = wk_win;  wp.p[2] = wv_win;
    wp.p[3] = wq_comp; wp.p[4] = wk_comp; wp.p[5] = wv_comp;
    wp.p[6] = wo;

    cvt_bf16<<<2048, 256, 0, stream>>>(x, XB);
    wt_cvt<<<dim3(32, 32, 7), 256, 0, stream>>>(wp, WT);
    gates_k<<<1024, 256, 0, stream>>>(x, w_gate, G1, G2);

    // ---- window branch (RoPE fused in GEMM epilogue) ----
    gemm_mfma<1><<<dim3(24, 32), 256, 0, stream>>>(XB, WT, QKV, QS, cosb, sinb);
    vmean_win_k<<<32, 256, 0, stream>>>(QKV + 2048, VMW);
    win_attn<<<dim3(8, 32), 256, 0, stream>>>(QKV, G1, OW);

    // ---- comp branch (reuses QKV) ----
    gemm_mfma<1><<<dim3(24, 32), 256, 0, stream>>>(XB, WT + 3 * 1048576, QKV, QS, cosb, sinb);
    comp_mlp<<<dim3(16, 32), 256, 0, stream>>>(QKV + 1024, QKV + 2048, w_mlp, KC, VC);
    mean_vc_k<<<32, 64, 0, stream>>>(VC, MVC);
    comp_attn<<<32, 256, 0, stream>>>(QKV, KC, VC, G2, OC);

    // ---- mix + output projection ----
    assemble<<<2048, 256, 0, stream>>>(OW, OC, VMW, MVC, G1, G2, FB);
    gemm_mfma<0><<<dim3(8, 32), 256, 0, stream>>>(FB, WT + 6 * 1048576, out, 1024, cosb, sinb);
}

// Round 11
// 370.933 us; speedup vs baseline: 1.6086x; 1.2934x over previous
//
#include <hip/hip_runtime.h>
#include <cmath>

// B=2, S=2048, DIM=1024, NH=16, HD=64, BLK=32, WIN=512.  M = B*S = 4096.
// Structure exploited:
//  - sel branch output == win branch output (sel projections dead)
//  - window attn: rows i<1536 fully masked -> uniform mean of v_win[1536:]
//  - comp attn: rows i<1984 fully masked -> uniform mean of 64 compressed v rows
//  - comp MLP == [4096x2048]@[2048x64] bf16 GEMM (K-rows || V-rows stacked)
//  - ROW COMPACTION: win QKV only needed for rows 1536..2047 per batch (1/4);
//    comp Q only needed for rows 1984..2047 per batch (128 rows total)
// Precision: GEMMs bf16 MFMA (fp32 accum), attention/softmax fp32.
// RoPE fused into GEMM epilogue; final mix assembled directly to bf16.

#define QS 3072   // QKV row stride (q|k|v)

typedef unsigned short ushort_t;
typedef __attribute__((ext_vector_type(4))) float f32x4;
typedef __attribute__((ext_vector_type(8))) short s8b;
typedef __attribute__((ext_vector_type(8))) unsigned short u16x8;

__device__ __forceinline__ unsigned short f2bf(float f) {
    unsigned u = __float_as_uint(f);
    u += 0x7FFF + ((u >> 16) & 1);
    return (unsigned short)(u >> 16);
}

__device__ __forceinline__ void gload16(const void* g, void* l) {
    __builtin_amdgcn_global_load_lds(
        (const __attribute__((address_space(1))) unsigned int*)g,
        (__attribute__((address_space(3))) unsigned int*)l, 16, 0, 0);
}

// Row maps for compacted GEMMs. RMODE 0: linear. RMODE 1: win rows
// (by in 0..7 -> batch rows 1536..2047). RMODE 2: comp-q rows (128 rows:
// r<64 -> b0 1984+r, r>=64 -> b1 1984+(r-64)).
template <int RMODE>
__device__ __forceinline__ int grow_of(int by, int r) {
    if constexpr (RMODE == 1) return (by >> 2) * 2048 + 1536 + (by & 3) * 128 + r;
    else if constexpr (RMODE == 2) return (r >> 6) * 2048 + 1984 + (r & 63);
    else return by * 128 + r;
}

// ---------------------------------------------------------------------------
// fp32 -> bf16 (8 elem / thread)
// ---------------------------------------------------------------------------
__global__ __launch_bounds__(256) void cvt_bf16(const float* __restrict__ in,
                                                ushort_t* __restrict__ outp) {
    int id = blockIdx.x * 256 + threadIdx.x;
    const float4* xp = (const float4*)in;
    float4 a = xp[id * 2], b = xp[id * 2 + 1];
    u16x8 o;
    o[0] = f2bf(a.x); o[1] = f2bf(a.y); o[2] = f2bf(a.z); o[3] = f2bf(a.w);
    o[4] = f2bf(b.x); o[5] = f2bf(b.y); o[6] = f2bf(b.z); o[7] = f2bf(b.w);
    *(u16x8*)&outp[id * 8] = o;
}

// ---------------------------------------------------------------------------
// Weight convert + transpose: WT[wi][n][k] = bf16(w_wi[k][n])  (1024x1024 each)
// ---------------------------------------------------------------------------
struct WPtrs { const float* p[7]; };

__global__ __launch_bounds__(256) void wt_cvt(WPtrs wp, ushort_t* __restrict__ WT) {
    __shared__ float T[32][33];
    const int wi = blockIdx.z;
    const float* w = wp.p[wi];
    const int k0 = blockIdx.y * 32, n0 = blockIdx.x * 32;
    const int t = threadIdx.x;
    const int row = t >> 3, c4 = t & 7;
    float4 v = *(const float4*)&w[(size_t)(k0 + row) * 1024 + n0 + c4 * 4];
    T[row][c4 * 4 + 0] = v.x; T[row][c4 * 4 + 1] = v.y;
    T[row][c4 * 4 + 2] = v.z; T[row][c4 * 4 + 3] = v.w;
    __syncthreads();
    ushort4 o;
    o.x = f2bf(T[c4 * 4 + 0][row]);
    o.y = f2bf(T[c4 * 4 + 1][row]);
    o.z = f2bf(T[c4 * 4 + 2][row]);
    o.w = f2bf(T[c4 * 4 + 3][row]);
    *(ushort4*)&WT[((size_t)wi << 20) + (size_t)(n0 + row) * 1024 + k0 + c4 * 4] = o;
}

// w_comp_mlp [2048][64] -> WTM [64][2048] bf16 (transpose-convert)
__global__ __launch_bounds__(256) void wmlp_cvt(const float* __restrict__ w,
                                                ushort_t* __restrict__ WTM) {
    __shared__ float T[32][33];
    const int k0 = blockIdx.x * 32;   // 64 tiles
    const int n0 = blockIdx.y * 32;   // 2 tiles
    const int t = threadIdx.x;
    const int row = t >> 3, c4 = t & 7;
    float4 v = *(const float4*)&w[(size_t)(k0 + row) * 64 + n0 + c4 * 4];
    T[row][c4 * 4 + 0] = v.x; T[row][c4 * 4 + 1] = v.y;
    T[row][c4 * 4 + 2] = v.z; T[row][c4 * 4 + 3] = v.w;
    __syncthreads();
    ushort4 o;
    o.x = f2bf(T[c4 * 4 + 0][row]);
    o.y = f2bf(T[c4 * 4 + 1][row]);
    o.z = f2bf(T[c4 * 4 + 2][row]);
    o.w = f2bf(T[c4 * 4 + 3][row]);
    *(ushort4*)&WTM[(size_t)(n0 + row) * 2048 + k0 + c4 * 4] = o;
}

// ---------------------------------------------------------------------------
// bf16 MFMA GEMM, m97 structure. 128x128 tile, BK=32, 256 thr, 2x2 waves.
// ROPE=1: fused RoPE on output columns < 2048.  RMODE: row map (see grow_of).
// nbase: column offset added to blockIdx.x*128 (selects weight via n0>>10).
// ---------------------------------------------------------------------------
template <int ROPE, int RMODE>
__global__ __launch_bounds__(256) void gemm_mfma(const ushort_t* __restrict__ A,
                                                 const ushort_t* __restrict__ WT,
                                                 float* __restrict__ C, int ldc,
                                                 const float* __restrict__ cosT,
                                                 const float* __restrict__ sinT,
                                                 int nbase) {
    __shared__ ushort_t Al[128 * 32];
    __shared__ ushort_t Bl[128 * 32];
    const int tid = threadIdx.x;
    const int wave = tid >> 6, lane = tid & 63;
    const int by = blockIdx.y;
    const int n0 = nbase + blockIdx.x * 128;
    const ushort_t* B = WT + ((size_t)(n0 >> 10) << 20) + (size_t)(n0 & 1023) * 1024;
    const int wr = wave >> 1, wc = wave & 1;
    f32x4 acc[4][4];
#pragma unroll
    for (int i = 0; i < 4; ++i)
#pragma unroll
        for (int j = 0; j < 4; ++j) acc[i][j] = (f32x4)0.f;

    for (int k0 = 0; k0 < 1024; k0 += 32) {
#pragma unroll
        for (int it = 0; it < 2; ++it) {
            const int chunk = it * 256 + wave * 64 + lane;
            const int row = chunk >> 2, slot = chunk & 3;
            gload16(A + (size_t)grow_of<RMODE>(by, row) * 1024 + k0 + slot * 8,
                    (char*)Al + (size_t)(it * 256 + wave * 64) * 16);
            gload16(B + (size_t)row * 1024 + k0 + slot * 8,
                    (char*)Bl + (size_t)(it * 256 + wave * 64) * 16);
        }
        __syncthreads();
        s8b af[4], bf[4];
        const int lr0 = lane & 15, lk = (lane >> 4) * 8;
#pragma unroll
        for (int f = 0; f < 4; ++f) {
            af[f] = *(const s8b*)&Al[(wr * 64 + f * 16 + lr0) * 32 + lk];
            bf[f] = *(const s8b*)&Bl[(wc * 64 + f * 16 + lr0) * 32 + lk];
        }
#pragma unroll
        for (int mi = 0; mi < 4; ++mi)
#pragma unroll
            for (int ni = 0; ni < 4; ++ni)
                acc[mi][ni] = __builtin_amdgcn_mfma_f32_16x16x32_bf16(
                    af[mi], bf[ni], acc[mi][ni], 0, 0, 0);
        __syncthreads();
    }
    const int lr = lane & 15, lq = lane >> 4;
    if (ROPE == 1 && n0 < 2048) {   // fused RoPE (q,k columns; head-local d = ni*16+lr)
#pragma unroll
        for (int mi = 0; mi < 4; ++mi)
#pragma unroll
            for (int r = 0; r < 4; ++r) {
                const int lrow = wr * 64 + mi * 16 + lq * 4 + r;
                const int sp = grow_of<RMODE>(by, lrow) & 2047;
#pragma unroll
                for (int ni = 0; ni < 2; ++ni) {
                    const int dd = ni * 16 + lr;
                    const float c = cosT[sp * 32 + dd];
                    const float sn = sinT[sp * 32 + dd];
                    const float a0 = acc[mi][ni][r], a2 = acc[mi][ni + 2][r];
                    acc[mi][ni][r]     = c * a0 - sn * a2;
                    acc[mi][ni + 2][r] = sn * a0 + c * a2;
                }
            }
    }
#pragma unroll
    for (int mi = 0; mi < 4; ++mi)
#pragma unroll
        for (int ni = 0; ni < 4; ++ni) {
            const int cn = n0 + wc * 64 + ni * 16 + lr;
#pragma unroll
            for (int r = 0; r < 4; ++r) {
                const int lrow = wr * 64 + mi * 16 + lq * 4 + r;
                C[(size_t)grow_of<RMODE>(by, lrow) * ldc + cn] = acc[mi][ni][r];
            }
        }
}

// ---------------------------------------------------------------------------
// Gather for comp MLP GEMM: AK/AV bf16 [2048][2048]
// row r = (b*16+h)*64 + jb ; col t = p*64+d = K/V[b][jb*32+p][h*64+d]
// ---------------------------------------------------------------------------
__global__ __launch_bounds__(256) void mlp_gather(const float* __restrict__ qkv,
                                                  ushort_t* __restrict__ AK,
                                                  ushort_t* __restrict__ AV) {
    int id = blockIdx.x * 256 + threadIdx.x;   // < 1,048,576
    int r = id >> 8;            // 0..4095 (K rows then V rows)
    int c = id & 255;
    int p = c >> 3, d0 = (c & 7) * 8;
    int side = r >> 11;
    int rr = r & 2047;
    int bh = rr >> 6, jb = rr & 63;
    int b = bh >> 4, h = bh & 15;
    const float* src = qkv + (size_t)(b * 2048 + jb * 32 + p) * QS +
                       (side ? 2048 : 1024) + h * 64 + d0;
    float4 a = *(const float4*)src;
    float4 bb = *(const float4*)(src + 4);
    u16x8 o;
    o[0] = f2bf(a.x); o[1] = f2bf(a.y); o[2] = f2bf(a.z); o[3] = f2bf(a.w);
    o[4] = f2bf(bb.x); o[5] = f2bf(bb.y); o[6] = f2bf(bb.z); o[7] = f2bf(bb.w);
    *(u16x8*)&((side ? AV : AK)[(size_t)rr * 2048 + c * 8]) = o;
}

// ---------------------------------------------------------------------------
// comp MLP GEMM: [128-row tile] x [64] over K=2048.
// A = AK (blocks 0..15) or AV (16..31); C -> KC or VC [2048][64] fp32.
// 4 waves, each 32 rows x 64 cols (acc[2][4]).
// ---------------------------------------------------------------------------
__global__ __launch_bounds__(256) void mlp_gemm(const ushort_t* __restrict__ AK,
                                                const ushort_t* __restrict__ AV,
                                                const ushort_t* __restrict__ WTM,
                                                float* __restrict__ KC,
                                                float* __restrict__ VC) {
    __shared__ ushort_t Al[128 * 32];
    __shared__ ushort_t Bl[64 * 32];
    const int tid = threadIdx.x;
    const int wave = tid >> 6, lane = tid & 63;
    const int m0g = blockIdx.x * 128;
    const int side = m0g >> 11;
    const int m0 = m0g & 2047;
    const ushort_t* A = side ? AV : AK;
    float* Cc = side ? VC : KC;
    f32x4 acc[2][4];
#pragma unroll
    for (int i = 0; i < 2; ++i)
#pragma unroll
        for (int j = 0; j < 4; ++j) acc[i][j] = (f32x4)0.f;

    for (int k0 = 0; k0 < 2048; k0 += 32) {
#pragma unroll
        for (int it = 0; it < 2; ++it) {
            const int chunk = it * 256 + wave * 64 + lane;
            const int row = chunk >> 2, slot = chunk & 3;
            gload16(A + (size_t)(m0 + row) * 2048 + k0 + slot * 8,
                    (char*)Al + (size_t)(it * 256 + wave * 64) * 16);
        }
        {
            const int row = tid >> 2, slot = tid & 3;
            gload16(WTM + (size_t)row * 2048 + k0 + slot * 8,
                    (char*)Bl + (size_t)(wave * 64) * 16);
        }
        __syncthreads();
        s8b af[2], bf4[4];
        const int lr0 = lane & 15, lk = (lane >> 4) * 8;
#pragma unroll
        for (int f = 0; f < 2; ++f)
            af[f] = *(const s8b*)&Al[(wave * 32 + f * 16 + lr0) * 32 + lk];
#pragma unroll
        for (int f = 0; f < 4; ++f)
            bf4[f] = *(const s8b*)&Bl[(f * 16 + lr0) * 32 + lk];
#pragma unroll
        for (int mi = 0; mi < 2; ++mi)
#pragma unroll
            for (int ni = 0; ni < 4; ++ni)
                acc[mi][ni] = __builtin_amdgcn_mfma_f32_16x16x32_bf16(
                    af[mi], bf4[ni], acc[mi][ni], 0, 0, 0);
        __syncthreads();
    }
    const int lr = lane & 15, lq = lane >> 4;
#pragma unroll
    for (int mi = 0; mi < 2; ++mi)
#pragma unroll
        for (int ni = 0; ni < 4; ++ni) {
            const int cm = m0 + wave * 32 + mi * 16 + lq * 4;
            const int cn = ni * 16 + lr;
#pragma unroll
            for (int r = 0; r < 4; ++r)
                Cc[(size_t)(cm + r) * 64 + cn] = acc[mi][ni][r];
        }
}

// ---------------------------------------------------------------------------
// Gates: softmax(x @ w_gate); g1 = g0+g2 (win+sel), g2 = g1 (comp)
// ---------------------------------------------------------------------------
__global__ __launch_bounds__(256) void gates_k(const float* __restrict__ x,
                                               const float* __restrict__ wg,
                                               float* __restrict__ g1,
                                               float* __restrict__ g2) {
    int lane = threadIdx.x & 63;
    int m = blockIdx.x * 4 + (threadIdx.x >> 6);
    float s0 = 0.f, s1 = 0.f, s2 = 0.f;
#pragma unroll
    for (int it = 0; it < 16; ++it) {
        int d = it * 64 + lane;
        float xv = x[(size_t)m * 1024 + d];
        s0 += xv * wg[d * 3 + 0];
        s1 += xv * wg[d * 3 + 1];
        s2 += xv * wg[d * 3 + 2];
    }
    for (int off = 32; off > 0; off >>= 1) {
        s0 += __shfl_xor(s0, off);
        s1 += __shfl_xor(s1, off);
        s2 += __shfl_xor(s2, off);
    }
    if (lane == 0) {
        float mx = fmaxf(s0, fmaxf(s1, s2));
        float e0 = __expf(s0 - mx), e1 = __expf(s1 - mx), e2 = __expf(s2 - mx);
        float inv = 1.f / (e0 + e1 + e2);
        g1[m] = (e0 + e2) * inv;
        g2[m] = e1 * inv;
    }
}

// mean of v_win over last 512 positions per (b,h); 256 thr: 4 partial sums
__global__ __launch_bounds__(256) void vmean_win_k(const float* __restrict__ v,
                                                   float* __restrict__ vmean) {
    __shared__ float red[4][64];
    int bh = blockIdx.x;
    int b = bh >> 4, h = bh & 15;
    int d = threadIdx.x & 63, sub = threadIdx.x >> 6;
    float a = 0.f;
#pragma unroll 8
    for (int p = 0; p < 128; ++p)
        a += v[(size_t)(b * 2048 + 1536 + sub * 128 + p) * QS + h * 64 + d];
    red[sub][d] = a;
    __syncthreads();
    if (sub == 0)
        vmean[bh * 64 + d] = (red[0][d] + red[1][d] + red[2][d] + red[3][d]) * (1.f / 512.f);
}

// ---------------------------------------------------------------------------
// Window attention rows 1536..2047, tile-parallel.
// Block 256 thr = 64 rows x 4 subs; grid (chunk 0..7, bh 0..31).
// Writes OW = g1 * out_win  (rows 1536.., layout [2][512][1024]).
// ---------------------------------------------------------------------------
__global__ __launch_bounds__(256) void win_attn(const float* __restrict__ qkv,
                                                const float* __restrict__ g1,
                                                float* __restrict__ OW) {
    __shared__ float Ks[64][68];
    __shared__ float Vs[64][68];
    __shared__ float Ps[64][68];
    const int chunk = blockIdx.x, bh = blockIdx.y;
    const int b = bh >> 4, h = bh & 15;
    const int t = threadIdx.x;
    const int rq = t >> 2, sub = t & 3;
    const int i = 1536 + chunk * 64 + rq;

    const float* qrow = qkv + (size_t)(b * 2048 + i) * QS + h * 64;
    float qreg[64];
#pragma unroll
    for (int d4 = 0; d4 < 16; ++d4) {
        float4 tt = *(const float4*)&qrow[d4 * 4];
        qreg[d4 * 4 + 0] = tt.x; qreg[d4 * 4 + 1] = tt.y;
        qreg[d4 * 4 + 2] = tt.z; qreg[d4 * 4 + 3] = tt.w;
    }
    float accv[16];
#pragma unroll
    for (int dd = 0; dd < 16; ++dd) accv[dd] = 0.f;
    float mrun = -1e30f, lrun = 0.f;
    const float* kg = qkv + 1024;
    const float* vg = qkv + 2048;

    for (int jt = 0; jt <= chunk; ++jt) {
        __syncthreads();
        {
            const size_t grow = (size_t)(b * 2048 + 1536 + jt * 64 + rq) * QS + h * 64 + sub * 16;
#pragma unroll
            for (int q4 = 0; q4 < 4; ++q4) {
                *(float4*)&Ks[rq][sub * 16 + q4 * 4] = *(const float4*)(kg + grow + q4 * 4);
                *(float4*)&Vs[rq][sub * 16 + q4 * 4] = *(const float4*)(vg + grow + q4 * 4);
            }
        }
        __syncthreads();
        const bool tail = (jt == chunk);
        float s[16];
#pragma unroll
        for (int jj = 0; jj < 16; ++jj) {
            const int j = jj * 4 + sub;          // conflict-free interleave
            float s0 = 0.f, s1 = 0.f, s2 = 0.f, s3 = 0.f;
#pragma unroll
            for (int d4 = 0; d4 < 16; ++d4) {
                float4 kv = *(const float4*)&Ks[j][d4 * 4];
                s0 += qreg[d4 * 4 + 0] * kv.x;
                s1 += qreg[d4 * 4 + 1] * kv.y;
                s2 += qreg[d4 * 4 + 2] * kv.z;
                s3 += qreg[d4 * 4 + 3] * kv.w;
            }
            float sd = ((s0 + s1) + (s2 + s3)) * 0.125f;
            if (tail && j > rq) sd = -1e30f;
            s[jj] = sd;
        }
        float mx = s[0];
#pragma unroll
        for (int jj = 1; jj < 16; ++jj) mx = fmaxf(mx, s[jj]);
        mx = fmaxf(mx, __shfl_xor(mx, 1));
        mx = fmaxf(mx, __shfl_xor(mx, 2));
        const float mnew = fmaxf(mrun, mx);
        const float scl = __expf(mrun - mnew);
        float psum = 0.f;
#pragma unroll
        for (int jj = 0; jj < 16; ++jj) {
            float pe = __expf(s[jj] - mnew);
            Ps[rq][jj * 4 + sub] = pe;
            psum += pe;
        }
        psum += __shfl_xor(psum, 1);
        psum += __shfl_xor(psum, 2);
        lrun = lrun * scl + psum;
        mrun = mnew;
#pragma unroll
        for (int dd = 0; dd < 16; ++dd) accv[dd] *= scl;
        __syncthreads();
        for (int j = 0; j < 64; ++j) {
            const float pv = Ps[rq][j];
#pragma unroll
            for (int d4 = 0; d4 < 4; ++d4) {
                float4 vv = *(const float4*)&Vs[j][sub * 16 + d4 * 4];
                accv[d4 * 4 + 0] += pv * vv.x;
                accv[d4 * 4 + 1] += pv * vv.y;
                accv[d4 * 4 + 2] += pv * vv.z;
                accv[d4 * 4 + 3] += pv * vv.w;
            }
        }
    }
    const float g = g1[b * 2048 + i] / lrun;
    float* orow = OW + (size_t)(b * 512 + i - 1536) * 1024 + h * 64 + sub * 16;
#pragma unroll
    for (int d4 = 0; d4 < 4; ++d4) {
        float4 o;
        o.x = accv[d4 * 4 + 0] * g; o.y = accv[d4 * 4 + 1] * g;
        o.z = accv[d4 * 4 + 2] * g; o.w = accv[d4 * 4 + 3] * g;
        *(float4*)&orow[d4 * 4] = o;
    }
}

__global__ void mean_vc_k(const float* __restrict__ vc, float* __restrict__ mvc) {
    int bh = blockIdx.x;
    int d = threadIdx.x;
    float a = 0.f;
#pragma unroll 8
    for (int jb = 0; jb < 64; ++jb) a += vc[((size_t)bh * 64 + jb) * 64 + d];
    mvc[bh * 64 + d] = a * (1.f / 64.f);
}

// ---------------------------------------------------------------------------
// Comp attention rows 1984..2047, tile-parallel (single 64-key tile).
// Block 256 thr = 64 rows x 4 subs; grid 32 (bh). OC = g2 * out_comp.
// ---------------------------------------------------------------------------
__global__ __launch_bounds__(256) void comp_attn(const float* __restrict__ qkv,
                                                 const float* __restrict__ kc,
                                                 const float* __restrict__ vc,
                                                 const float* __restrict__ g2,
                                                 float* __restrict__ OC) {
    __shared__ float Ks[64][68];
    __shared__ float Vs[64][68];
    __shared__ float Ps[64][68];
    const int bh = blockIdx.x;
    const int b = bh >> 4, h = bh & 15;
    const int t = threadIdx.x;
    const int rq = t >> 2, sub = t & 3;
    const int i = 1984 + rq;
    {
        const size_t src = ((size_t)bh * 64 + rq) * 64 + sub * 16;
#pragma unroll
        for (int q4 = 0; q4 < 4; ++q4) {
            *(float4*)&Ks[rq][sub * 16 + q4 * 4] = *(const float4*)&kc[src + q4 * 4];
            *(float4*)&Vs[rq][sub * 16 + q4 * 4] = *(const float4*)&vc[src + q4 * 4];
        }
    }
    const float* qrow = qkv + (size_t)(b * 2048 + i) * QS + h * 64;
    float qreg[64];
#pragma unroll
    for (int d4 = 0; d4 < 16; ++d4) {
        float4 tt = *(const float4*)&qrow[d4 * 4];
        qreg[d4 * 4 + 0] = tt.x; qreg[d4 * 4 + 1] = tt.y;
        qreg[d4 * 4 + 2] = tt.z; qreg[d4 * 4 + 3] = tt.w;
    }
    __syncthreads();
    float s[16];
#pragma unroll
    for (int jj = 0; jj < 16; ++jj) {
        const int j = jj * 4 + sub;
        float s0 = 0.f, s1 = 0.f, s2 = 0.f, s3 = 0.f;
#pragma unroll
        for (int d4 = 0; d4 < 16; ++d4) {
            float4 kv = *(const float4*)&Ks[j][d4 * 4];
            s0 += qreg[d4 * 4 + 0] * kv.x;
            s1 += qreg[d4 * 4 + 1] * kv.y;
            s2 += qreg[d4 * 4 + 2] * kv.z;
            s3 += qreg[d4 * 4 + 3] * kv.w;
        }
        float sd = ((s0 + s1) + (s2 + s3)) * 0.125f;
        if (j > rq) sd = -1e30f;   // causal: row 1984+rq attends blocks 0..rq
        s[jj] = sd;
    }
    float mx = s[0];
#pragma unroll
    for (int jj = 1; jj < 16; ++jj) mx = fmaxf(mx, s[jj]);
    mx = fmaxf(mx, __shfl_xor(mx, 1));
    mx = fmaxf(mx, __shfl_xor(mx, 2));
    float psum = 0.f;
#pragma unroll
    for (int jj = 0; jj < 16; ++jj) {
        float pe = __expf(s[jj] - mx);
        Ps[rq][jj * 4 + sub] = pe;
        psum += pe;
    }
    psum += __shfl_xor(psum, 1);
    psum += __shfl_xor(psum, 2);
    __syncthreads();
    float accv[16];
#pragma unroll
    for (int dd = 0; dd < 16; ++dd) accv[dd] = 0.f;
    for (int j = 0; j < 64; ++j) {
        const float pv = Ps[rq][j];
#pragma unroll
        for (int d4 = 0; d4 < 4; ++d4) {
            float4 vv = *(const float4*)&Vs[j][sub * 16 + d4 * 4];
            accv[d4 * 4 + 0] += pv * vv.x;
            accv[d4 * 4 + 1] += pv * vv.y;
            accv[d4 * 4 + 2] += pv * vv.z;
            accv[d4 * 4 + 3] += pv * vv.w;
        }
    }
    const float g = g2[b * 2048 + i] / psum;
    float* orow = OC + (size_t)(b * 64 + rq) * 1024 + h * 64 + sub * 16;
#pragma unroll
    for (int d4 = 0; d4 < 4; ++d4) {
        float4 o;
        o.x = accv[d4 * 4 + 0] * g; o.y = accv[d4 * 4 + 1] * g;
        o.z = accv[d4 * 4 + 2] * g; o.w = accv[d4 * 4 + 3] * g;
        *(float4*)&orow[d4 * 4] = o;
    }
}

// ---------------------------------------------------------------------------
// Final mix -> bf16.  8 cols / thread.
//  i<1536:        g1*vmean + g2*mvc
//  1536<=i<1984:  OW + g2*mvc        (OW pre-scaled by g1)
//  i>=1984:       OW + OC            (OC pre-scaled by g2)
// ---------------------------------------------------------------------------
__global__ __launch_bounds__(256) void assemble(const float* __restrict__ OW,
                                                const float* __restrict__ OC,
                                                const float* __restrict__ vmean,
                                                const float* __restrict__ mvc,
                                                const float* __restrict__ g1,
                                                const float* __restrict__ g2,
                                                ushort_t* __restrict__ FB) {
    int id = blockIdx.x * 256 + threadIdx.x;   // < 524288
    int m = id >> 7, cg = id & 127;
    int b = m >> 11, i = m & 2047;
    int h = cg >> 3, d0 = (cg & 7) * 8;
    int bh = b * 16 + h;
    float g1v = g1[m], g2v = g2[m];
    float vals[8];
    if (i < 1536) {
#pragma unroll
        for (int kk = 0; kk < 8; ++kk)
            vals[kk] = g1v * vmean[bh * 64 + d0 + kk] + g2v * mvc[bh * 64 + d0 + kk];
    } else if (i < 1984) {
        const float* ow = OW + (size_t)(b * 512 + i - 1536) * 1024 + cg * 8;
#pragma unroll
        for (int kk = 0; kk < 8; ++kk)
            vals[kk] = ow[kk] + g2v * mvc[bh * 64 + d0 + kk];
    } else {
        const float* ow = OW + (size_t)(b * 512 + i - 1536) * 1024 + cg * 8;
        const float* oc = OC + (size_t)(b * 64 + i - 1984) * 1024 + cg * 8;
#pragma unroll
        for (int kk = 0; kk < 8; ++kk)
            vals[kk] = ow[kk] + oc[kk];
    }
    u16x8 o;
#pragma unroll
    for (int kk = 0; kk < 8; ++kk) o[kk] = f2bf(vals[kk]);
    *(u16x8*)&FB[(size_t)m * 1024 + cg * 8] = o;
}

// ---------------------------------------------------------------------------
extern "C" void kernel_launch(void* const* d_in, const int* in_sizes, int n_in,
                              void* d_out, int out_size, void* d_ws, size_t ws_size,
                              hipStream_t stream) {
    const float* x       = (const float*)d_in[0];
    const float* wq_win  = (const float*)d_in[1];
    const float* wk_win  = (const float*)d_in[2];
    const float* wv_win  = (const float*)d_in[3];
    // d_in[4..6] sel weights unused (out_sel == out_win)
    const float* wq_comp = (const float*)d_in[7];
    const float* wk_comp = (const float*)d_in[8];
    const float* wv_comp = (const float*)d_in[9];
    const float* w_mlp   = (const float*)d_in[10];
    const float* w_gate  = (const float*)d_in[11];
    const float* wo      = (const float*)d_in[12];
    const float* cosb    = (const float*)d_in[13];
    const float* sinb    = (const float*)d_in[14];
    float* out = (float*)d_out;

    char* wsb = (char*)d_ws;
    ushort_t* XB = (ushort_t*)wsb;                      // 8 MB bf16 x
    ushort_t* WT = (ushort_t*)(wsb + (8u << 20));       // 14 MB transposed bf16 weights
    float* QKV   = (float*)(wsb + (22u << 20));         // 48 MB [4096][3072]
    ushort_t* FB = (ushort_t*)(wsb + (70u << 20));      // 8 MB bf16 mixed output
    float* OW    = (float*)(wsb + (78u << 20));         // 4 MB [2][512][1024]
    float* OC    = (float*)(wsb + (82u << 20));         // 512 KB [2][64][1024]
    float* KC    = (float*)(wsb + (83u << 20));         // 512 KB [2048][64]
    float* VC    = KC + 131072;                         // 512 KB
    float* VMW   = VC + 131072;
    float* MVC   = VMW + 2048;
    float* G1    = MVC + 2048;
    float* G2    = G1 + 4096;
    ushort_t* WTM = (ushort_t*)(wsb + (85u << 20));     // 256 KB [64][2048]
    // comp-MLP A buffers alias dead windows at their point in the stream:
    ushort_t* AK = FB;                                  // 8 MB (FB written later)
    ushort_t* AV = XB;                                  // 8 MB (XB dead after compQ GEMM)

    WPtrs wp;
    wp.p[0] = wq_win;  wp.p[1] = wk_win;  wp.p[2] = wv_win;
    wp.p[3] = wq_comp; wp.p[4] = wk_comp; wp.p[5] = wv_comp;
    wp.p[6] = wo;

    cvt_bf16<<<2048, 256, 0, stream>>>(x, XB);
    wt_cvt<<<dim3(32, 32, 7), 256, 0, stream>>>(wp, WT);
    wmlp_cvt<<<dim3(64, 2), 256, 0, stream>>>(w_mlp, WTM);
    gates_k<<<1024, 256, 0, stream>>>(x, w_gate, G1, G2);

    // ---- window branch: QKV only for rows 1536..2047 per batch (RMODE 1) ----
    gemm_mfma<1, 1><<<dim3(24, 8), 256, 0, stream>>>(XB, WT, QKV, QS, cosb, sinb, 0);
    vmean_win_k<<<32, 256, 0, stream>>>(QKV + 2048, VMW);
    win_attn<<<dim3(8, 32), 256, 0, stream>>>(QKV, G1, OW);

    // ---- comp branch: K,V for all rows (cols 1024..3071); Q for 128 rows ----
    gemm_mfma<1, 0><<<dim3(16, 32), 256, 0, stream>>>(XB, WT + 3 * 1048576, QKV, QS,
                                                      cosb, sinb, 1024);
    gemm_mfma<1, 2><<<dim3(8, 1), 256, 0, stream>>>(XB, WT + 3 * 1048576, QKV, QS,
                                                    cosb, sinb, 0);
    mlp_gather<<<4096, 256, 0, stream>>>(QKV, AK, AV);
    mlp_gemm<<<32, 256, 0, stream>>>(AK, AV, WTM, KC, VC);
    mean_vc_k<<<32, 64, 0, stream>>>(VC, MVC);
    comp_attn<<<32, 256, 0, stream>>>(QKV, KC, VC, G2, OC);

    // ---- mix + output projection (FB safe: AK consumed by mlp_gemm above) ----
    assemble<<<2048, 256, 0, stream>>>(OW, OC, VMW, MVC, G1, G2, FB);
    gemm_mfma<0, 0><<<dim3(8, 32), 256, 0, stream>>>(FB, WT + 6 * 1048576, out, 1024,
                                                     cosb, sinb, 0);
}